// Round 2
// baseline (907.115 us; speedup 1.0000x reference)
//
#include <hip/hip_runtime.h>
#include <hip/hip_bf16.h>
#include <cmath>

#define NNODES 100000
#define NEDGES 1600000
#define INF 256
#define HH 4
#define DD 32
#define HD 128
#define NEG_SLOPE 0.2f

// ---------------- transpose weights: Wt[k][j] = (j<128 ? fc_w[j][k] : res_w[j-128][k])
__global__ void transpose_w_kernel(const float* __restrict__ fc_w,
                                   const float* __restrict__ res_w,
                                   float* __restrict__ Wt) {
    int idx = blockIdx.x * blockDim.x + threadIdx.x;
    if (idx >= 256 * 256) return;
    int k = idx >> 8;
    int j = idx & 255;
    float v = (j < 128) ? fc_w[j * 256 + k] : res_w[(j - 128) * 256 + k];
    Wt[k * 256 + j] = v;
}

// ---------------- dual GEMM: out[n][j] = sum_k feat[n][k] * Wt[k][j]
// j<128 -> ft (ws), j>=128 -> res (written into d_out rst region)
#define BM 64
#define BN 256
#define BK 32
__global__ __launch_bounds__(256) void gemm_kernel(const float* __restrict__ feat,
                                                   const float* __restrict__ Wt,
                                                   float* __restrict__ ft,
                                                   float* __restrict__ res) {
    __shared__ float As[BM][BK];   // 8 KB
    __shared__ float Bs[BK][BN];   // 32 KB
    const int tid = threadIdx.x;
    const int block_row = blockIdx.x * BM;
    const int tr = tid >> 5;       // 0..7  (8 row-groups)
    const int tc = tid & 31;       // 0..31 (col within group)

    float acc[8][8];
#pragma unroll
    for (int i = 0; i < 8; ++i)
#pragma unroll
        for (int j = 0; j < 8; ++j) acc[i][j] = 0.f;

    for (int k0 = 0; k0 < INF; k0 += BK) {
        // stage A: 64x32 floats = 512 float4, 2 per thread
#pragma unroll
        for (int i = tid; i < BM * BK / 4; i += 256) {
            int row = i >> 3;
            int kq  = (i & 7) << 2;
            int grow = block_row + row;
            float4 v = make_float4(0.f, 0.f, 0.f, 0.f);
            if (grow < NNODES)
                v = *(const float4*)&feat[(size_t)grow * INF + k0 + kq];
            *(float4*)&As[row][kq] = v;
        }
        // stage B: 32x256 floats = 2048 float4, 8 per thread
#pragma unroll
        for (int i = tid; i < BK * BN / 4; i += 256) {
            int kr = i >> 6;
            int jq = (i & 63) << 2;
            *(float4*)&Bs[kr][jq] = *(const float4*)&Wt[(k0 + kr) * 256 + jq];
        }
        __syncthreads();
#pragma unroll
        for (int kk = 0; kk < BK; ++kk) {
            float a[8], b[8];
#pragma unroll
            for (int ri = 0; ri < 8; ++ri) a[ri] = As[tr * 8 + ri][kk];
#pragma unroll
            for (int ci = 0; ci < 8; ++ci) b[ci] = Bs[kk][tc + 32 * ci];
#pragma unroll
            for (int ri = 0; ri < 8; ++ri)
#pragma unroll
                for (int ci = 0; ci < 8; ++ci) acc[ri][ci] += a[ri] * b[ci];
        }
        __syncthreads();
    }
    // write back
#pragma unroll
    for (int ri = 0; ri < 8; ++ri) {
        int grow = block_row + tr * 8 + ri;
        if (grow >= NNODES) break;
#pragma unroll
        for (int ci = 0; ci < 8; ++ci) {
            int j = tc + 32 * ci;
            float v = acc[ri][ci];
            if (j < HD) ft[(size_t)grow * HD + j] = v;
            else        res[(size_t)grow * HD + (j - HD)] = v;
        }
    }
}

// ---------------- per-(n,h) attention logits
__global__ void el_er_kernel(const float* __restrict__ ft,
                             const float* __restrict__ attn_l,
                             const float* __restrict__ attn_r,
                             float* __restrict__ el, float* __restrict__ er) {
    int idx = blockIdx.x * blockDim.x + threadIdx.x;
    if (idx >= NNODES * HH) return;
    int n = idx >> 2, h = idx & 3;
    const float* f = &ft[(size_t)n * HD + h * DD];
    float sl = 0.f, sr = 0.f;
#pragma unroll
    for (int d = 0; d < DD; ++d) {
        float v = f[d];
        sl += v * attn_l[h * DD + d];
        sr += v * attn_r[h * DD + d];
    }
    el[idx] = sl;
    er[idx] = sr;
}

// ---------------- degree histogram over dst
__global__ void hist_kernel(const int* __restrict__ dst, int* __restrict__ deg) {
    int e = blockIdx.x * blockDim.x + threadIdx.x;
    if (e < NEDGES) atomicAdd(&deg[dst[e]], 1);
}

// ---------------- 3-phase exclusive scan (1024 elems / block)
__global__ __launch_bounds__(256) void scan1_kernel(const int* __restrict__ deg,
                                                    int* __restrict__ excl,
                                                    int* __restrict__ blockSums) {
    __shared__ int sdata[256];
    int b = blockIdx.x, t = threadIdx.x;
    int base = b * 1024 + t * 4;
    int v[4];
#pragma unroll
    for (int i = 0; i < 4; ++i) {
        int idx = base + i;
        v[i] = (idx < NNODES) ? deg[idx] : 0;
    }
    int tsum = v[0] + v[1] + v[2] + v[3];
    sdata[t] = tsum;
    __syncthreads();
    for (int off = 1; off < 256; off <<= 1) {
        int x = (t >= off) ? sdata[t - off] : 0;
        __syncthreads();
        sdata[t] += x;
        __syncthreads();
    }
    int texcl = sdata[t] - tsum;
    if (t == 255) blockSums[b] = sdata[255];
    int run = texcl;
#pragma unroll
    for (int i = 0; i < 4; ++i) {
        int idx = base + i;
        if (idx < NNODES) excl[idx] = run;
        run += v[i];
    }
}

__global__ void scan2_kernel(int* __restrict__ blockSums, int nb) {
    if (threadIdx.x == 0 && blockIdx.x == 0) {
        int run = 0;
        for (int i = 0; i < nb; ++i) { int v = blockSums[i]; blockSums[i] = run; run += v; }
    }
}

__global__ void scan3_kernel(int* __restrict__ excl, int* __restrict__ cursor,
                             const int* __restrict__ blockSums) {
    int idx = blockIdx.x * blockDim.x + threadIdx.x;
    if (idx < NNODES) {
        int v = excl[idx] + blockSums[idx >> 10];
        excl[idx] = v;
        cursor[idx] = v;
    }
}

// ---------------- per-edge: ex = exp(leaky(el[src]+er[dst])), scatter CSR-ordered
__global__ void edge_kernel(const int* __restrict__ src, const int* __restrict__ dst,
                            const float* __restrict__ el, const float* __restrict__ er,
                            int* __restrict__ cursor, int* __restrict__ csr_src,
                            float* __restrict__ csr_ex) {
    int e = blockIdx.x * blockDim.x + threadIdx.x;
    if (e >= NEDGES) return;
    int s = src[e], d = dst[e];
    float4 l = *(const float4*)&el[(size_t)s * 4];
    float4 r = *(const float4*)&er[(size_t)d * 4];
    float4 x;
    float t;
    t = l.x + r.x; t = (t > 0.f) ? t : NEG_SLOPE * t; x.x = expf(t);
    t = l.y + r.y; t = (t > 0.f) ? t : NEG_SLOPE * t; x.y = expf(t);
    t = l.z + r.z; t = (t > 0.f) ? t : NEG_SLOPE * t; x.z = expf(t);
    t = l.w + r.w; t = (t > 0.f) ? t : NEG_SLOPE * t; x.w = expf(t);
    int pos = atomicAdd(&cursor[d], 1);
    csr_src[pos] = s;
    *(float4*)&csr_ex[(size_t)pos * 4] = x;
}

// ---------------- per-node aggregation (no float atomics)
__global__ __launch_bounds__(128) void agg_kernel(const int* __restrict__ offsets,
                                                  const int* __restrict__ deg,
                                                  const int* __restrict__ csr_src,
                                                  const float* __restrict__ csr_ex,
                                                  const float* __restrict__ ft,
                                                  float* __restrict__ out_rst,
                                                  float* __restrict__ out_agg) {
    int n = blockIdx.x;
    int c = threadIdx.x;       // channel 0..127
    int h = c >> 5;
    int start = offsets[n];
    int dg = deg[n];
    float acc = 0.f, den = 0.f;
    for (int i = 0; i < dg; ++i) {
        int s = csr_src[start + i];
        float ex = csr_ex[(size_t)(start + i) * 4 + h];
        acc += ex * ft[(size_t)s * HD + c];
        den += ex;
    }
    float agg = (dg > 0) ? acc / den : 0.f;
    size_t o = (size_t)n * HD + c;
    out_agg[o] = agg;
    out_rst[o] = agg + out_rst[o];   // res was staged there by gemm
}

// ---------------- launch
extern "C" void kernel_launch(void* const* d_in, const int* in_sizes, int n_in,
                              void* d_out, int out_size, void* d_ws, size_t ws_size,
                              hipStream_t stream) {
    const float* feat   = (const float*)d_in[0];
    const int*   src    = (const int*)d_in[1];
    const int*   dst    = (const int*)d_in[2];
    const float* fc_w   = (const float*)d_in[3];
    const float* attn_l = (const float*)d_in[4];
    const float* attn_r = (const float*)d_in[5];
    const float* res_w  = (const float*)d_in[6];

    float* out_rst = (float*)d_out;                       // [N][128]
    float* out_agg = out_rst + (size_t)NNODES * HD;       // [N][128]

    // workspace layout (256B aligned)
    char* p = (char*)d_ws;
    auto alloc = [&](size_t bytes) {
        char* r = p;
        p += (bytes + 255) & ~(size_t)255;
        return (void*)r;
    };
    float* ft        = (float*)alloc((size_t)NNODES * HD * 4);   // 51.2 MB
    float* Wt        = (float*)alloc(256 * 256 * 4);             // 256 KB
    float* el        = (float*)alloc((size_t)NNODES * HH * 4);   // 1.6 MB
    float* er        = (float*)alloc((size_t)NNODES * HH * 4);   // 1.6 MB
    float* csr_ex    = (float*)alloc((size_t)NEDGES * HH * 4);   // 25.6 MB
    int*   deg       = (int*)alloc((size_t)NNODES * 4);
    int*   offsets   = (int*)alloc((size_t)NNODES * 4);
    int*   cursor    = (int*)alloc((size_t)NNODES * 4);
    int*   blockSums = (int*)alloc(1024);
    int*   csr_src   = (int*)alloc((size_t)NEDGES * 4);          // 6.4 MB

    const int nb_scan = (NNODES + 1023) / 1024;                  // 98

    hipMemsetAsync(deg, 0, (size_t)NNODES * 4, stream);

    transpose_w_kernel<<<(256 * 256) / 256, 256, 0, stream>>>(fc_w, res_w, Wt);
    gemm_kernel<<<(NNODES + BM - 1) / BM, 256, 0, stream>>>(feat, Wt, ft, out_rst);
    el_er_kernel<<<(NNODES * HH + 255) / 256, 256, 0, stream>>>(ft, attn_l, attn_r, el, er);
    hist_kernel<<<(NEDGES + 255) / 256, 256, 0, stream>>>(dst, deg);
    scan1_kernel<<<nb_scan, 256, 0, stream>>>(deg, offsets, blockSums);
    scan2_kernel<<<1, 64, 0, stream>>>(blockSums, nb_scan);
    scan3_kernel<<<(NNODES + 255) / 256, 256, 0, stream>>>(offsets, cursor, blockSums);
    edge_kernel<<<(NEDGES + 255) / 256, 256, 0, stream>>>(src, dst, el, er, cursor, csr_src, csr_ex);
    agg_kernel<<<NNODES, 128, 0, stream>>>(offsets, deg, csr_src, csr_ex, ft, out_rst, out_agg);
}

// Round 3
// 613.650 us; speedup vs baseline: 1.4782x; 1.4782x over previous
//
#include <hip/hip_runtime.h>
#include <hip/hip_bf16.h>
#include <cmath>

#define NNODES 100000
#define NEDGES 1600000
#define INF 256
#define HH 4
#define DD 32
#define HD 128
#define NEG_SLOPE 0.2f

typedef __attribute__((ext_vector_type(8))) short short8;   // 8 bf16 = 4 VGPR
typedef __attribute__((ext_vector_type(4))) float f32x4;    // MFMA C/D frag

// ---------------- pack weights to bf16: W2[j][k], j<128 = fc_w rows, j>=128 = res_w rows
__global__ void w2_kernel(const float* __restrict__ fc_w,
                          const float* __restrict__ res_w,
                          __hip_bfloat16* __restrict__ W2) {
    int idx = blockIdx.x * blockDim.x + threadIdx.x;   // 65536
    int j = idx >> 8;
    int k = idx & 255;
    float v = (j < 128) ? fc_w[j * 256 + k] : res_w[(j - 128) * 256 + k];
    W2[idx] = __float2bfloat16(v);
}

// ---------------- MFMA dual GEMM: C[n][j] = sum_k feat[n][k] * W2[j][k]
// blockIdx.y==0 -> j in [0,128)  -> ft (bf16, ws)
// blockIdx.y==1 -> j in [128,256)-> res (f32, staged into out_rst)
// Tile: BM=128 x BN=128, BK=64. 256 threads = 4 waves (2x2), each wave 64x64.
#define GBM 128
#define GBK 64
__global__ __launch_bounds__(256) void gemm_kernel(const float* __restrict__ feat,
                                                   const __hip_bfloat16* __restrict__ W2,
                                                   __hip_bfloat16* __restrict__ ft,
                                                   float* __restrict__ res) {
    // swizzled LDS tiles: [128 rows][64 bf16 = 128 B], byte off = row*128 + (bc ^ ((row&7)<<4))
    __shared__ __align__(16) char Asm[GBM * GBK * 2];   // 16 KB
    __shared__ __align__(16) char Bsm[GBM * GBK * 2];   // 16 KB

    const int tid  = threadIdx.x;
    const int lane = tid & 63;
    const int wv   = tid >> 6;        // 0..3
    const int wr   = wv >> 1;         // wave row 0..1 (64 rows each)
    const int wc   = wv & 1;          // wave col 0..1 (64 cols each)
    const int lrow = lane & 15;
    const int lk   = lane >> 4;       // 0..3
    const int m0   = blockIdx.x * GBM;
    const int j0   = blockIdx.y * 128;

    f32x4 acc[4][4];
#pragma unroll
    for (int m = 0; m < 4; ++m)
#pragma unroll
        for (int n = 0; n < 4; ++n) acc[m][n] = (f32x4){0.f, 0.f, 0.f, 0.f};

    for (int k0 = 0; k0 < INF; k0 += GBK) {
        if (k0) __syncthreads();
        // ---- stage A (f32 -> bf16) and B (bf16 copy), 4 chunks of 16B each per thread
#pragma unroll
        for (int i = 0; i < 4; ++i) {
            int c   = tid + 256 * i;        // 0..1023
            int row = c >> 3;               // 0..127
            int cb  = c & 7;                // 16B chunk within 128B row
            int off = row * 128 + ((cb * 16) ^ ((row & 7) << 4));
            // A
            int grow = m0 + row;
            float4 f0 = make_float4(0.f, 0.f, 0.f, 0.f), f1 = f0;
            if (grow < NNODES) {
                const float* gp = &feat[(size_t)grow * INF + k0 + cb * 8];
                f0 = *(const float4*)gp;
                f1 = *(const float4*)(gp + 4);
            }
            union { short8 v; __hip_bfloat16 h[8]; } pk;
            pk.h[0] = __float2bfloat16(f0.x); pk.h[1] = __float2bfloat16(f0.y);
            pk.h[2] = __float2bfloat16(f0.z); pk.h[3] = __float2bfloat16(f0.w);
            pk.h[4] = __float2bfloat16(f1.x); pk.h[5] = __float2bfloat16(f1.y);
            pk.h[6] = __float2bfloat16(f1.z); pk.h[7] = __float2bfloat16(f1.w);
            *(short8*)(Asm + off) = pk.v;
            // B: W2 row j0+row, cols k0+cb*8 .. +8 (16B)
            *(short8*)(Bsm + off) = *(const short8*)&W2[(size_t)(j0 + row) * 256 + k0 + cb * 8];
        }
        __syncthreads();
        // ---- compute: 2 K-steps of 32
#pragma unroll
        for (int ks = 0; ks < 2; ++ks) {
            short8 a[4], b[4];
#pragma unroll
            for (int m = 0; m < 4; ++m) {
                int row = wr * 64 + m * 16 + lrow;
                int bc  = ks * 64 + lk * 16;
                a[m] = *(const short8*)(Asm + row * 128 + (bc ^ ((row & 7) << 4)));
            }
#pragma unroll
            for (int n = 0; n < 4; ++n) {
                int row = wc * 64 + n * 16 + lrow;
                int bc  = ks * 64 + lk * 16;
                b[n] = *(const short8*)(Bsm + row * 128 + (bc ^ ((row & 7) << 4)));
            }
#pragma unroll
            for (int m = 0; m < 4; ++m)
#pragma unroll
                for (int n = 0; n < 4; ++n)
                    acc[m][n] = __builtin_amdgcn_mfma_f32_16x16x32_bf16(a[m], b[n], acc[m][n], 0, 0, 0);
        }
    }

    // ---- epilogue: C/D frag mapping col=lane&15, row=(lane>>4)*4+reg
#pragma unroll
    for (int m = 0; m < 4; ++m) {
        int rbase = m0 + wr * 64 + m * 16 + lk * 4;
#pragma unroll
        for (int n = 0; n < 4; ++n) {
            int col = wc * 64 + n * 16 + lrow;        // 0..127 within this j-half
#pragma unroll
            for (int r = 0; r < 4; ++r) {
                int grow = rbase + r;
                if (grow >= NNODES) continue;
                float v = acc[m][n][r];
                if (blockIdx.y == 0) ft[(size_t)grow * HD + col] = __float2bfloat16(v);
                else                 res[(size_t)grow * HD + col] = v;
            }
        }
    }
}

// ---------------- per-(n,h) attention logits (coalesced: 128 lanes = 1 node)
__global__ __launch_bounds__(256) void el_er_kernel(const __hip_bfloat16* __restrict__ ft,
                                                    const float* __restrict__ attn_l,
                                                    const float* __restrict__ attn_r,
                                                    float* __restrict__ el, float* __restrict__ er) {
    int t = threadIdx.x;
    int n = blockIdx.x * 2 + (t >> 7);
    if (n >= NNODES) return;
    int c = t & 127;
    float v = __bfloat162float(ft[(size_t)n * HD + c]);
    float sl = v * attn_l[c];
    float sr = v * attn_r[c];
#pragma unroll
    for (int m = 16; m; m >>= 1) {
        sl += __shfl_xor(sl, m);
        sr += __shfl_xor(sr, m);
    }
    if ((c & 31) == 0) {
        el[n * HH + (c >> 5)] = sl;
        er[n * HH + (c >> 5)] = sr;
    }
}

// ---------------- degree histogram over dst
__global__ void hist_kernel(const int* __restrict__ dst, int* __restrict__ deg) {
    int e = blockIdx.x * blockDim.x + threadIdx.x;
    if (e < NEDGES) atomicAdd(&deg[dst[e]], 1);
}

// ---------------- 3-phase exclusive scan (1024 elems / block)
__global__ __launch_bounds__(256) void scan1_kernel(const int* __restrict__ deg,
                                                    int* __restrict__ excl,
                                                    int* __restrict__ blockSums) {
    __shared__ int sdata[256];
    int b = blockIdx.x, t = threadIdx.x;
    int base = b * 1024 + t * 4;
    int v[4];
#pragma unroll
    for (int i = 0; i < 4; ++i) {
        int idx = base + i;
        v[i] = (idx < NNODES) ? deg[idx] : 0;
    }
    int tsum = v[0] + v[1] + v[2] + v[3];
    sdata[t] = tsum;
    __syncthreads();
    for (int off = 1; off < 256; off <<= 1) {
        int x = (t >= off) ? sdata[t - off] : 0;
        __syncthreads();
        sdata[t] += x;
        __syncthreads();
    }
    int texcl = sdata[t] - tsum;
    if (t == 255) blockSums[b] = sdata[255];
    int run = texcl;
#pragma unroll
    for (int i = 0; i < 4; ++i) {
        int idx = base + i;
        if (idx < NNODES) excl[idx] = run;
        run += v[i];
    }
}

__global__ void scan2_kernel(int* __restrict__ blockSums, int nb) {
    if (threadIdx.x == 0 && blockIdx.x == 0) {
        int run = 0;
        for (int i = 0; i < nb; ++i) { int v = blockSums[i]; blockSums[i] = run; run += v; }
    }
}

__global__ void scan3_kernel(int* __restrict__ excl, int* __restrict__ cursor,
                             const int* __restrict__ blockSums) {
    int idx = blockIdx.x * blockDim.x + threadIdx.x;
    if (idx < NNODES) {
        int v = excl[idx] + blockSums[idx >> 10];
        excl[idx] = v;
        cursor[idx] = v;
    }
}

// ---------------- per-edge: ex = exp(leaky(el[src]+er[dst])), scatter CSR-ordered
__global__ void edge_kernel(const int* __restrict__ src, const int* __restrict__ dst,
                            const float* __restrict__ el, const float* __restrict__ er,
                            int* __restrict__ cursor, int* __restrict__ csr_src,
                            float* __restrict__ csr_ex) {
    int e = blockIdx.x * blockDim.x + threadIdx.x;
    if (e >= NEDGES) return;
    int s = src[e], d = dst[e];
    float4 l = *(const float4*)&el[(size_t)s * 4];
    float4 r = *(const float4*)&er[(size_t)d * 4];
    float4 x;
    float t;
    t = l.x + r.x; t = (t > 0.f) ? t : NEG_SLOPE * t; x.x = expf(t);
    t = l.y + r.y; t = (t > 0.f) ? t : NEG_SLOPE * t; x.y = expf(t);
    t = l.z + r.z; t = (t > 0.f) ? t : NEG_SLOPE * t; x.z = expf(t);
    t = l.w + r.w; t = (t > 0.f) ? t : NEG_SLOPE * t; x.w = expf(t);
    int pos = atomicAdd(&cursor[d], 1);
    csr_src[pos] = s;
    *(float4*)&csr_ex[(size_t)pos * 4] = x;
}

// ---------------- per-node aggregation (no float atomics)
__global__ __launch_bounds__(128) void agg_kernel(const int* __restrict__ offsets,
                                                  const int* __restrict__ deg,
                                                  const int* __restrict__ csr_src,
                                                  const float* __restrict__ csr_ex,
                                                  const __hip_bfloat16* __restrict__ ft,
                                                  float* __restrict__ out_rst,
                                                  float* __restrict__ out_agg) {
    int n = blockIdx.x;
    int c = threadIdx.x;       // channel 0..127
    int h = c >> 5;
    int start = offsets[n];
    int dg = deg[n];
    float acc = 0.f, den = 0.f;
    for (int i = 0; i < dg; ++i) {
        int s = csr_src[start + i];
        float ex = csr_ex[(size_t)(start + i) * 4 + h];
        acc += ex * __bfloat162float(ft[(size_t)s * HD + c]);
        den += ex;
    }
    float agg = (dg > 0) ? acc / den : 0.f;
    size_t o = (size_t)n * HD + c;
    out_agg[o] = agg;
    out_rst[o] = agg + out_rst[o];   // res was staged there by gemm (blockIdx.y==1)
}

// ---------------- launch
extern "C" void kernel_launch(void* const* d_in, const int* in_sizes, int n_in,
                              void* d_out, int out_size, void* d_ws, size_t ws_size,
                              hipStream_t stream) {
    const float* feat   = (const float*)d_in[0];
    const int*   src    = (const int*)d_in[1];
    const int*   dst    = (const int*)d_in[2];
    const float* fc_w   = (const float*)d_in[3];
    const float* attn_l = (const float*)d_in[4];
    const float* attn_r = (const float*)d_in[5];
    const float* res_w  = (const float*)d_in[6];

    float* out_rst = (float*)d_out;                       // [N][128]
    float* out_agg = out_rst + (size_t)NNODES * HD;       // [N][128]

    // workspace layout (256B aligned)
    char* p = (char*)d_ws;
    auto alloc = [&](size_t bytes) {
        char* r = p;
        p += (bytes + 255) & ~(size_t)255;
        return (void*)r;
    };
    __hip_bfloat16* ft = (__hip_bfloat16*)alloc((size_t)NNODES * HD * 2);  // 25.6 MB
    __hip_bfloat16* W2 = (__hip_bfloat16*)alloc(256 * 256 * 2);            // 128 KB
    float* el        = (float*)alloc((size_t)NNODES * HH * 4);             // 1.6 MB
    float* er        = (float*)alloc((size_t)NNODES * HH * 4);             // 1.6 MB
    float* csr_ex    = (float*)alloc((size_t)NEDGES * HH * 4);             // 25.6 MB
    int*   deg       = (int*)alloc((size_t)NNODES * 4);
    int*   offsets   = (int*)alloc((size_t)NNODES * 4);
    int*   cursor    = (int*)alloc((size_t)NNODES * 4);
    int*   blockSums = (int*)alloc(1024);
    int*   csr_src   = (int*)alloc((size_t)NEDGES * 4);                    // 6.4 MB

    const int nb_scan = (NNODES + 1023) / 1024;                            // 98

    hipMemsetAsync(deg, 0, (size_t)NNODES * 4, stream);

    w2_kernel<<<256, 256, 0, stream>>>(fc_w, res_w, W2);
    dim3 ggrid((NNODES + GBM - 1) / GBM, 2);
    gemm_kernel<<<ggrid, 256, 0, stream>>>(feat, W2, ft, out_rst);
    el_er_kernel<<<NNODES / 2, 256, 0, stream>>>(ft, attn_l, attn_r, el, er);
    hist_kernel<<<(NEDGES + 255) / 256, 256, 0, stream>>>(dst, deg);
    scan1_kernel<<<nb_scan, 256, 0, stream>>>(deg, offsets, blockSums);
    scan2_kernel<<<1, 64, 0, stream>>>(blockSums, nb_scan);
    scan3_kernel<<<(NNODES + 255) / 256, 256, 0, stream>>>(offsets, cursor, blockSums);
    edge_kernel<<<(NEDGES + 255) / 256, 256, 0, stream>>>(src, dst, el, er, cursor, csr_src, csr_ex);
    agg_kernel<<<NNODES, 128, 0, stream>>>(offsets, deg, csr_src, csr_ex, ft, out_rst, out_agg);
}

// Round 5
// 546.067 us; speedup vs baseline: 1.6612x; 1.1238x over previous
//
#include <hip/hip_runtime.h>
#include <hip/hip_bf16.h>
#include <cmath>

#define NNODES 100000
#define NEDGES 1600000
#define INF 256
#define HH 4
#define DD 32
#define HD 128
#define NEG_SLOPE 0.2f

typedef __attribute__((ext_vector_type(8))) short short8;   // 8 bf16 = 4 VGPR
typedef __attribute__((ext_vector_type(4))) float f32x4;    // MFMA C/D frag

// ---------------- pack weights to bf16: W2[j][k], j<128 = fc_w rows, j>=128 = res_w rows
__global__ void w2_kernel(const float* __restrict__ fc_w,
                          const float* __restrict__ res_w,
                          __hip_bfloat16* __restrict__ W2) {
    int idx = blockIdx.x * blockDim.x + threadIdx.x;   // 65536
    int j = idx >> 8;
    int k = idx & 255;
    float v = (j < 128) ? fc_w[j * 256 + k] : res_w[(j - 128) * 256 + k];
    W2[idx] = __float2bfloat16(v);
}

// ---------------- MFMA dual GEMM: C[n][j] = sum_k feat[n][k] * W2[j][k]
// blockIdx.y==0 -> j in [0,128)  -> ft (bf16, ws)
// blockIdx.y==1 -> j in [128,256)-> res (f32, staged into out_rst)
// Tile: BM=128 x BN=128, BK=64. 256 threads = 4 waves (2x2), each wave 64x64.
#define GBM 128
#define GBK 64
__global__ __launch_bounds__(256) void gemm_kernel(const float* __restrict__ feat,
                                                   const __hip_bfloat16* __restrict__ W2,
                                                   __hip_bfloat16* __restrict__ ft,
                                                   float* __restrict__ res) {
    // swizzled LDS tiles: [128 rows][64 bf16 = 128 B], byte off = row*128 + (bc ^ ((row&7)<<4))
    __shared__ __align__(16) char Asm[GBM * GBK * 2];   // 16 KB
    __shared__ __align__(16) char Bsm[GBM * GBK * 2];   // 16 KB

    const int tid  = threadIdx.x;
    const int lane = tid & 63;
    const int wv   = tid >> 6;        // 0..3
    const int wr   = wv >> 1;         // wave row 0..1 (64 rows each)
    const int wc   = wv & 1;          // wave col 0..1 (64 cols each)
    const int lrow = lane & 15;
    const int lk   = lane >> 4;       // 0..3
    const int m0   = blockIdx.x * GBM;
    const int j0   = blockIdx.y * 128;

    f32x4 acc[4][4];
#pragma unroll
    for (int m = 0; m < 4; ++m)
#pragma unroll
        for (int n = 0; n < 4; ++n) acc[m][n] = (f32x4){0.f, 0.f, 0.f, 0.f};

    for (int k0 = 0; k0 < INF; k0 += GBK) {
        if (k0) __syncthreads();
        // ---- stage A (f32 -> bf16) and B (bf16 copy), 4 chunks of 16B each per thread
#pragma unroll
        for (int i = 0; i < 4; ++i) {
            int c   = tid + 256 * i;        // 0..1023
            int row = c >> 3;               // 0..127
            int cb  = c & 7;                // 16B chunk within 128B row
            int off = row * 128 + ((cb * 16) ^ ((row & 7) << 4));
            // A
            int grow = m0 + row;
            float4 f0 = make_float4(0.f, 0.f, 0.f, 0.f), f1 = f0;
            if (grow < NNODES) {
                const float* gp = &feat[(size_t)grow * INF + k0 + cb * 8];
                f0 = *(const float4*)gp;
                f1 = *(const float4*)(gp + 4);
            }
            union { short8 v; __hip_bfloat16 h[8]; } pk;
            pk.h[0] = __float2bfloat16(f0.x); pk.h[1] = __float2bfloat16(f0.y);
            pk.h[2] = __float2bfloat16(f0.z); pk.h[3] = __float2bfloat16(f0.w);
            pk.h[4] = __float2bfloat16(f1.x); pk.h[5] = __float2bfloat16(f1.y);
            pk.h[6] = __float2bfloat16(f1.z); pk.h[7] = __float2bfloat16(f1.w);
            *(short8*)(Asm + off) = pk.v;
            // B: W2 row j0+row, cols k0+cb*8 .. +8 (16B)
            *(short8*)(Bsm + off) = *(const short8*)&W2[(size_t)(j0 + row) * 256 + k0 + cb * 8];
        }
        __syncthreads();
        // ---- compute: 2 K-steps of 32
#pragma unroll
        for (int ks = 0; ks < 2; ++ks) {
            short8 a[4], b[4];
#pragma unroll
            for (int m = 0; m < 4; ++m) {
                int row = wr * 64 + m * 16 + lrow;
                int bc  = ks * 64 + lk * 16;
                a[m] = *(const short8*)(Asm + row * 128 + (bc ^ ((row & 7) << 4)));
            }
#pragma unroll
            for (int n = 0; n < 4; ++n) {
                int row = wc * 64 + n * 16 + lrow;
                int bc  = ks * 64 + lk * 16;
                b[n] = *(const short8*)(Bsm + row * 128 + (bc ^ ((row & 7) << 4)));
            }
#pragma unroll
            for (int m = 0; m < 4; ++m)
#pragma unroll
                for (int n = 0; n < 4; ++n)
                    acc[m][n] = __builtin_amdgcn_mfma_f32_16x16x32_bf16(a[m], b[n], acc[m][n], 0, 0, 0);
        }
    }

    // ---- epilogue: C/D frag mapping col=lane&15, row=(lane>>4)*4+reg
#pragma unroll
    for (int m = 0; m < 4; ++m) {
        int rbase = m0 + wr * 64 + m * 16 + lk * 4;
#pragma unroll
        for (int n = 0; n < 4; ++n) {
            int col = wc * 64 + n * 16 + lrow;        // 0..127 within this j-half
#pragma unroll
            for (int r = 0; r < 4; ++r) {
                int grow = rbase + r;
                if (grow >= NNODES) continue;
                float v = acc[m][n][r];
                if (blockIdx.y == 0) ft[(size_t)grow * HD + col] = __float2bfloat16(v);
                else                 res[(size_t)grow * HD + col] = v;
            }
        }
    }
}

// ---------------- per-(n,h) attention logits (coalesced: 128 lanes = 1 node)
__global__ __launch_bounds__(256) void el_er_kernel(const __hip_bfloat16* __restrict__ ft,
                                                    const float* __restrict__ attn_l,
                                                    const float* __restrict__ attn_r,
                                                    float* __restrict__ el, float* __restrict__ er) {
    int t = threadIdx.x;
    int n = blockIdx.x * 2 + (t >> 7);
    if (n >= NNODES) return;
    int c = t & 127;
    float v = __bfloat162float(ft[(size_t)n * HD + c]);
    float sl = v * attn_l[c];
    float sr = v * attn_r[c];
#pragma unroll
    for (int m = 16; m; m >>= 1) {
        sl += __shfl_xor(sl, m);
        sr += __shfl_xor(sr, m);
    }
    if ((c & 31) == 0) {
        el[n * HH + (c >> 5)] = sl;
        er[n * HH + (c >> 5)] = sr;
    }
}

// ---------------- degree histogram over dst
__global__ void hist_kernel(const int* __restrict__ dst, int* __restrict__ deg) {
    int e = blockIdx.x * blockDim.x + threadIdx.x;
    if (e < NEDGES) atomicAdd(&deg[dst[e]], 1);
}

// ---------------- 3-phase exclusive scan (1024 elems / block)
__global__ __launch_bounds__(256) void scan1_kernel(const int* __restrict__ deg,
                                                    int* __restrict__ excl,
                                                    int* __restrict__ blockSums) {
    __shared__ int sdata[256];
    int b = blockIdx.x, t = threadIdx.x;
    int base = b * 1024 + t * 4;
    int v[4];
#pragma unroll
    for (int i = 0; i < 4; ++i) {
        int idx = base + i;
        v[i] = (idx < NNODES) ? deg[idx] : 0;
    }
    int tsum = v[0] + v[1] + v[2] + v[3];
    sdata[t] = tsum;
    __syncthreads();
    for (int off = 1; off < 256; off <<= 1) {
        int x = (t >= off) ? sdata[t - off] : 0;
        __syncthreads();
        sdata[t] += x;
        __syncthreads();
    }
    int texcl = sdata[t] - tsum;
    if (t == 255) blockSums[b] = sdata[255];
    int run = texcl;
#pragma unroll
    for (int i = 0; i < 4; ++i) {
        int idx = base + i;
        if (idx < NNODES) excl[idx] = run;
        run += v[i];
    }
}

__global__ void scan2_kernel(int* __restrict__ blockSums, int nb) {
    if (threadIdx.x == 0 && blockIdx.x == 0) {
        int run = 0;
        for (int i = 0; i < nb; ++i) { int v = blockSums[i]; blockSums[i] = run; run += v; }
    }
}

__global__ void scan3_kernel(int* __restrict__ excl, int* __restrict__ cursor,
                             const int* __restrict__ blockSums) {
    int idx = blockIdx.x * blockDim.x + threadIdx.x;
    if (idx < NNODES) {
        int v = excl[idx] + blockSums[idx >> 10];
        excl[idx] = v;
        cursor[idx] = v;
    }
}

// ---------------- per-edge: ex = exp(leaky(el[src]+er[dst])), scatter CSR-ordered
__global__ void edge_kernel(const int* __restrict__ src, const int* __restrict__ dst,
                            const float* __restrict__ el, const float* __restrict__ er,
                            int* __restrict__ cursor, int* __restrict__ csr_src,
                            float* __restrict__ csr_ex) {
    int e = blockIdx.x * blockDim.x + threadIdx.x;
    if (e >= NEDGES) return;
    int s = src[e], d = dst[e];
    float4 l = *(const float4*)&el[(size_t)s * 4];
    float4 r = *(const float4*)&er[(size_t)d * 4];
    float4 x;
    float t;
    t = l.x + r.x; t = (t > 0.f) ? t : NEG_SLOPE * t; x.x = expf(t);
    t = l.y + r.y; t = (t > 0.f) ? t : NEG_SLOPE * t; x.y = expf(t);
    t = l.z + r.z; t = (t > 0.f) ? t : NEG_SLOPE * t; x.z = expf(t);
    t = l.w + r.w; t = (t > 0.f) ? t : NEG_SLOPE * t; x.w = expf(t);
    int pos = atomicAdd(&cursor[d], 1);
    csr_src[pos] = s;
    *(float4*)&csr_ex[(size_t)pos * 4] = x;
}

// ---------------- per-node aggregation, 4-edge batched for memory-level parallelism
__global__ __launch_bounds__(128) void agg_kernel(const int* __restrict__ offsets,
                                                  const int* __restrict__ deg,
                                                  const int* __restrict__ csr_src,
                                                  const float* __restrict__ csr_ex,
                                                  const __hip_bfloat16* __restrict__ ft,
                                                  float* __restrict__ out_rst,
                                                  float* __restrict__ out_agg) {
    int n = blockIdx.x;
    int c = threadIdx.x;       // channel 0..127
    int h = c >> 5;
    int start = offsets[n];
    int dg = deg[n];
    const __hip_bfloat16* ftc = ft + c;

    float acc0 = 0.f, acc1 = 0.f, acc2 = 0.f, acc3 = 0.f;
    float den0 = 0.f, den1 = 0.f, den2 = 0.f, den3 = 0.f;
    int last = start + dg - 1;

    for (int i = 0; i < dg; i += 4) {
        // clamped indices: all loads always issued (batched, 12 independent loads in flight)
        int j0 = start + i;
        int j1 = (i + 1 < dg) ? j0 + 1 : last;
        int j2 = (i + 2 < dg) ? j0 + 2 : last;
        int j3 = (i + 3 < dg) ? j0 + 3 : last;
        int s0 = csr_src[j0];
        int s1 = csr_src[j1];
        int s2 = csr_src[j2];
        int s3 = csr_src[j3];
        float e0 = csr_ex[(size_t)j0 * 4 + h];
        float e1 = csr_ex[(size_t)j1 * 4 + h];
        float e2 = csr_ex[(size_t)j2 * 4 + h];
        float e3 = csr_ex[(size_t)j3 * 4 + h];
        float f0 = __bfloat162float(ftc[(size_t)s0 * HD]);
        float f1 = __bfloat162float(ftc[(size_t)s1 * HD]);
        float f2 = __bfloat162float(ftc[(size_t)s2 * HD]);
        float f3 = __bfloat162float(ftc[(size_t)s3 * HD]);
        // zero-mask the clamped duplicates
        if (i + 1 >= dg) e1 = 0.f;
        if (i + 2 >= dg) e2 = 0.f;
        if (i + 3 >= dg) e3 = 0.f;
        acc0 += e0 * f0; acc1 += e1 * f1; acc2 += e2 * f2; acc3 += e3 * f3;
        den0 += e0;      den1 += e1;      den2 += e2;      den3 += e3;
    }

    float acc = (acc0 + acc1) + (acc2 + acc3);
    float den = (den0 + den1) + (den2 + den3);
    float agg = (dg > 0) ? acc / den : 0.f;
    size_t o = (size_t)n * HD + c;
    out_agg[o] = agg;
    out_rst[o] = agg + out_rst[o];   // res was staged there by gemm (blockIdx.y==1)
}

// ---------------- launch
extern "C" void kernel_launch(void* const* d_in, const int* in_sizes, int n_in,
                              void* d_out, int out_size, void* d_ws, size_t ws_size,
                              hipStream_t stream) {
    const float* feat   = (const float*)d_in[0];
    const int*   src    = (const int*)d_in[1];
    const int*   dst    = (const int*)d_in[2];
    const float* fc_w   = (const float*)d_in[3];
    const float* attn_l = (const float*)d_in[4];
    const float* attn_r = (const float*)d_in[5];
    const float* res_w  = (const float*)d_in[6];

    float* out_rst = (float*)d_out;                       // [N][128]
    float* out_agg = out_rst + (size_t)NNODES * HD;       // [N][128]

    // workspace layout (256B aligned)
    char* p = (char*)d_ws;
    auto alloc = [&](size_t bytes) {
        char* r = p;
        p += (bytes + 255) & ~(size_t)255;
        return (void*)r;
    };
    __hip_bfloat16* ft = (__hip_bfloat16*)alloc((size_t)NNODES * HD * 2);  // 25.6 MB
    __hip_bfloat16* W2 = (__hip_bfloat16*)alloc(256 * 256 * 2);            // 128 KB
    float* el        = (float*)alloc((size_t)NNODES * HH * 4);             // 1.6 MB
    float* er        = (float*)alloc((size_t)NNODES * HH * 4);             // 1.6 MB
    float* csr_ex    = (float*)alloc((size_t)NEDGES * HH * 4);             // 25.6 MB
    int*   deg       = (int*)alloc((size_t)NNODES * 4);
    int*   offsets   = (int*)alloc((size_t)NNODES * 4);
    int*   cursor    = (int*)alloc((size_t)NNODES * 4);
    int*   blockSums = (int*)alloc(1024);
    int*   csr_src   = (int*)alloc((size_t)NEDGES * 4);                    // 6.4 MB

    const int nb_scan = (NNODES + 1023) / 1024;                            // 98

    hipMemsetAsync(deg, 0, (size_t)NNODES * 4, stream);

    w2_kernel<<<256, 256, 0, stream>>>(fc_w, res_w, W2);
    dim3 ggrid((NNODES + GBM - 1) / GBM, 2);
    gemm_kernel<<<ggrid, 256, 0, stream>>>(feat, W2, ft, out_rst);
    el_er_kernel<<<NNODES / 2, 256, 0, stream>>>(ft, attn_l, attn_r, el, er);
    hist_kernel<<<(NEDGES + 255) / 256, 256, 0, stream>>>(dst, deg);
    scan1_kernel<<<nb_scan, 256, 0, stream>>>(deg, offsets, blockSums);
    scan2_kernel<<<1, 64, 0, stream>>>(blockSums, nb_scan);
    scan3_kernel<<<(NNODES + 255) / 256, 256, 0, stream>>>(offsets, cursor, blockSums);
    edge_kernel<<<(NEDGES + 255) / 256, 256, 0, stream>>>(src, dst, el, er, cursor, csr_src, csr_ex);
    agg_kernel<<<NNODES, 128, 0, stream>>>(offsets, deg, csr_src, csr_ex, ft, out_rst, out_agg);
}

// Round 6
// 490.704 us; speedup vs baseline: 1.8486x; 1.1128x over previous
//
#include <hip/hip_runtime.h>
#include <hip/hip_bf16.h>
#include <cmath>

#define NNODES 100000
#define NEDGES 1600000
#define INF 256
#define HH 4
#define DD 32
#define HD 128
#define NEG_SLOPE 0.2f

typedef __attribute__((ext_vector_type(8))) short short8;   // 8 bf16 = 4 VGPR
typedef __attribute__((ext_vector_type(4))) float f32x4;    // MFMA C/D frag

// ---------------- fused dual GEMM + el/er:
// C[n][j] = sum_k feat[n][k] * W[j][k],  W = [fc_w ; res_w] (256 rows)
// j<128 -> ft (bf16, ws); j>=128 -> res (f32, staged into out_rst)
// el[n,h] = sum_{col in head h} C[n][col]*attn_l[col]  (computed from f32 acc)
// Tile: BM=64 x BN=256, BK=64. 256 threads = 4 waves; wave wc owns cols [wc*64, wc*64+64).
#define GBM 64
#define GBK 64
__global__ __launch_bounds__(256) void gemm_kernel(const float* __restrict__ feat,
                                                   const float* __restrict__ fc_w,
                                                   const float* __restrict__ res_w,
                                                   const float* __restrict__ attn_l,
                                                   const float* __restrict__ attn_r,
                                                   __hip_bfloat16* __restrict__ ft,
                                                   float* __restrict__ out_rst,
                                                   float* __restrict__ el,
                                                   float* __restrict__ er) {
    // swizzled LDS: row of 64 bf16 = 128 B; byte off = row*128 + ((cb*16) ^ ((row&7)<<4))
    __shared__ __align__(16) char Asm[GBM * GBK * 2];    // 8 KB
    __shared__ __align__(16) char Bsm[256 * GBK * 2];    // 32 KB

    const int tid  = threadIdx.x;
    const int lane = tid & 63;
    const int wc   = tid >> 6;        // 0..3: col-slice [wc*64, wc*64+64)
    const int lrow = lane & 15;
    const int lk   = lane >> 4;       // 0..3
    const int m0   = blockIdx.x * GBM;

    f32x4 acc[4][4];
#pragma unroll
    for (int m = 0; m < 4; ++m)
#pragma unroll
        for (int n = 0; n < 4; ++n) acc[m][n] = (f32x4){0.f, 0.f, 0.f, 0.f};

    for (int k0 = 0; k0 < INF; k0 += GBK) {
        if (k0) __syncthreads();
        // ---- stage A (feat f32 -> bf16): 64 rows x 8 chunks = 512, 2/thread
#pragma unroll
        for (int i = 0; i < 2; ++i) {
            int c   = tid + 256 * i;
            int row = c >> 3;
            int cb  = c & 7;
            int off = row * 128 + ((cb * 16) ^ ((row & 7) << 4));
            int grow = m0 + row;
            float4 f0 = make_float4(0.f, 0.f, 0.f, 0.f), f1 = f0;
            if (grow < NNODES) {
                const float* gp = &feat[(size_t)grow * INF + k0 + cb * 8];
                f0 = *(const float4*)gp;
                f1 = *(const float4*)(gp + 4);
            }
            union { short8 v; __hip_bfloat16 h[8]; } pk;
            pk.h[0] = __float2bfloat16(f0.x); pk.h[1] = __float2bfloat16(f0.y);
            pk.h[2] = __float2bfloat16(f0.z); pk.h[3] = __float2bfloat16(f0.w);
            pk.h[4] = __float2bfloat16(f1.x); pk.h[5] = __float2bfloat16(f1.y);
            pk.h[6] = __float2bfloat16(f1.z); pk.h[7] = __float2bfloat16(f1.w);
            *(short8*)(Asm + off) = pk.v;
        }
        // ---- stage B (weights f32 -> bf16): 256 rows x 8 chunks = 2048, 8/thread
#pragma unroll
        for (int i = 0; i < 8; ++i) {
            int c   = tid + 256 * i;
            int row = c >> 3;
            int cb  = c & 7;
            int off = row * 128 + ((cb * 16) ^ ((row & 7) << 4));
            const float* wp = (row < 128) ? &fc_w[(size_t)row * 256]
                                          : &res_w[(size_t)(row - 128) * 256];
            float4 f0 = *(const float4*)&wp[k0 + cb * 8];
            float4 f1 = *(const float4*)&wp[k0 + cb * 8 + 4];
            union { short8 v; __hip_bfloat16 h[8]; } pk;
            pk.h[0] = __float2bfloat16(f0.x); pk.h[1] = __float2bfloat16(f0.y);
            pk.h[2] = __float2bfloat16(f0.z); pk.h[3] = __float2bfloat16(f0.w);
            pk.h[4] = __float2bfloat16(f1.x); pk.h[5] = __float2bfloat16(f1.y);
            pk.h[6] = __float2bfloat16(f1.z); pk.h[7] = __float2bfloat16(f1.w);
            *(short8*)(Bsm + off) = pk.v;
        }
        __syncthreads();
        // ---- compute: 2 K-steps of 32
#pragma unroll
        for (int ks = 0; ks < 2; ++ks) {
            short8 a[4], b[4];
            int bc = ks * 64 + lk * 16;
#pragma unroll
            for (int m = 0; m < 4; ++m) {
                int row = m * 16 + lrow;
                a[m] = *(const short8*)(Asm + row * 128 + (bc ^ ((row & 7) << 4)));
            }
#pragma unroll
            for (int n = 0; n < 4; ++n) {
                int row = wc * 64 + n * 16 + lrow;
                b[n] = *(const short8*)(Bsm + row * 128 + (bc ^ ((row & 7) << 4)));
            }
#pragma unroll
            for (int m = 0; m < 4; ++m)
#pragma unroll
                for (int n = 0; n < 4; ++n)
                    acc[m][n] = __builtin_amdgcn_mfma_f32_16x16x32_bf16(a[m], b[n], acc[m][n], 0, 0, 0);
        }
    }

    // ---- epilogue: C/D frag mapping col=lane&15, row=(lane>>4)*4+reg
    // attn scalars for this wave's cols (only meaningful for wc<2)
    float al[4], ar[4];
    if (wc < 2) {
#pragma unroll
        for (int n = 0; n < 4; ++n) {
            int col = wc * 64 + n * 16 + lrow;
            al[n] = attn_l[col];
            ar[n] = attn_r[col];
        }
    }
#pragma unroll
    for (int m = 0; m < 4; ++m) {
#pragma unroll
        for (int r = 0; r < 4; ++r) {
            int grow = m0 + m * 16 + lk * 4 + r;
            if (grow >= NNODES) continue;
            if (wc < 2) {
                // ft store + el/er partials
                float e_l0, e_l1, e_r0, e_r1;
                {
                    float v0 = acc[m][0][r], v1 = acc[m][1][r];
                    float v2 = acc[m][2][r], v3 = acc[m][3][r];
                    ft[(size_t)grow * HD + wc * 64 + 0 * 16 + lrow] = __float2bfloat16(v0);
                    ft[(size_t)grow * HD + wc * 64 + 1 * 16 + lrow] = __float2bfloat16(v1);
                    ft[(size_t)grow * HD + wc * 64 + 2 * 16 + lrow] = __float2bfloat16(v2);
                    ft[(size_t)grow * HD + wc * 64 + 3 * 16 + lrow] = __float2bfloat16(v3);
                    e_l0 = v0 * al[0] + v1 * al[1];   // head wc*2   (cols wc*64 .. +31)
                    e_l1 = v2 * al[2] + v3 * al[3];   // head wc*2+1 (cols wc*64+32 .. +63)
                    e_r0 = v0 * ar[0] + v1 * ar[1];
                    e_r1 = v2 * ar[2] + v3 * ar[3];
                }
                // reduce over lrow (16-lane group; masks stay within group)
#pragma unroll
                for (int msk = 1; msk < 16; msk <<= 1) {
                    e_l0 += __shfl_xor(e_l0, msk);
                    e_l1 += __shfl_xor(e_l1, msk);
                    e_r0 += __shfl_xor(e_r0, msk);
                    e_r1 += __shfl_xor(e_r1, msk);
                }
                if (lrow == 0) {
                    el[grow * HH + wc * 2 + 0] = e_l0;
                    el[grow * HH + wc * 2 + 1] = e_l1;
                    er[grow * HH + wc * 2 + 0] = e_r0;
                    er[grow * HH + wc * 2 + 1] = e_r1;
                }
            } else {
#pragma unroll
                for (int n = 0; n < 4; ++n) {
                    int col = wc * 64 + n * 16 + lrow - 128;
                    out_rst[(size_t)grow * HD + col] = acc[m][n][r];
                }
            }
        }
    }
}

// ---------------- degree histogram over dst
__global__ void hist_kernel(const int* __restrict__ dst, int* __restrict__ deg) {
    int e = blockIdx.x * blockDim.x + threadIdx.x;
    if (e < NEDGES) atomicAdd(&deg[dst[e]], 1);
}

// ---------------- 3-phase exclusive scan (1024 elems / block)
__global__ __launch_bounds__(256) void scan1_kernel(const int* __restrict__ deg,
                                                    int* __restrict__ excl,
                                                    int* __restrict__ blockSums) {
    __shared__ int sdata[256];
    int b = blockIdx.x, t = threadIdx.x;
    int base = b * 1024 + t * 4;
    int v[4];
#pragma unroll
    for (int i = 0; i < 4; ++i) {
        int idx = base + i;
        v[i] = (idx < NNODES) ? deg[idx] : 0;
    }
    int tsum = v[0] + v[1] + v[2] + v[3];
    sdata[t] = tsum;
    __syncthreads();
    for (int off = 1; off < 256; off <<= 1) {
        int x = (t >= off) ? sdata[t - off] : 0;
        __syncthreads();
        sdata[t] += x;
        __syncthreads();
    }
    int texcl = sdata[t] - tsum;
    if (t == 255) blockSums[b] = sdata[255];
    int run = texcl;
#pragma unroll
    for (int i = 0; i < 4; ++i) {
        int idx = base + i;
        if (idx < NNODES) excl[idx] = run;
        run += v[i];
    }
}

// parallel exclusive scan of the 98 block sums (single block, 128 threads)
__global__ void scan2_kernel(int* __restrict__ blockSums, int nb) {
    __shared__ int sd[128];
    int t = threadIdx.x;
    int v = (t < nb) ? blockSums[t] : 0;
    sd[t] = v;
    __syncthreads();
    for (int off = 1; off < 128; off <<= 1) {
        int x = (t >= off) ? sd[t - off] : 0;
        __syncthreads();
        sd[t] += x;
        __syncthreads();
    }
    if (t < nb) blockSums[t] = sd[t] - v;
}

__global__ void scan3_kernel(int* __restrict__ excl, int* __restrict__ cursor,
                             const int* __restrict__ blockSums) {
    int idx = blockIdx.x * blockDim.x + threadIdx.x;
    if (idx < NNODES) {
        int v = excl[idx] + blockSums[idx >> 10];
        excl[idx] = v;
        cursor[idx] = v;
    }
}

// ---------------- per-edge: ex = exp(leaky(el[src]+er[dst])), scatter CSR-ordered
__global__ void edge_kernel(const int* __restrict__ src, const int* __restrict__ dst,
                            const float* __restrict__ el, const float* __restrict__ er,
                            int* __restrict__ cursor, int* __restrict__ csr_src,
                            float* __restrict__ csr_ex) {
    int e = blockIdx.x * blockDim.x + threadIdx.x;
    if (e >= NEDGES) return;
    int s = src[e], d = dst[e];
    float4 l = *(const float4*)&el[(size_t)s * 4];
    float4 r = *(const float4*)&er[(size_t)d * 4];
    float4 x;
    float t;
    t = l.x + r.x; t = (t > 0.f) ? t : NEG_SLOPE * t; x.x = expf(t);
    t = l.y + r.y; t = (t > 0.f) ? t : NEG_SLOPE * t; x.y = expf(t);
    t = l.z + r.z; t = (t > 0.f) ? t : NEG_SLOPE * t; x.z = expf(t);
    t = l.w + r.w; t = (t > 0.f) ? t : NEG_SLOPE * t; x.w = expf(t);
    int pos = atomicAdd(&cursor[d], 1);
    csr_src[pos] = s;
    *(float4*)&csr_ex[(size_t)pos * 4] = x;
}

// ---------------- per-node aggregation: wave-per-node, shfl-broadcast indices,
// 16 independent gathers in flight per chunk. lane l -> channels 2l, 2l+1.
__global__ __launch_bounds__(256) void agg_kernel(const int* __restrict__ offsets,
                                                  const int* __restrict__ deg,
                                                  const int* __restrict__ csr_src,
                                                  const float* __restrict__ csr_ex,
                                                  const ushort* __restrict__ ft2,
                                                  float* __restrict__ out_rst,
                                                  float* __restrict__ out_agg) {
    const int w = threadIdx.x >> 6;
    const int l = threadIdx.x & 63;
    const int n = blockIdx.x * 4 + w;
    if (n >= NNODES) return;
    const int start = offsets[n];
    const int dg    = deg[n];
    const int h     = l >> 4;

    float acc0 = 0.f, acc1 = 0.f, den = 0.f;

    for (int base = 0; base < dg; base += 16) {
        // stage 16 edges: lanes cooperatively load src (16 lanes' worth, replicated)
        // and ex components: lane l holds component (l>>4) of edge (l&15) -> 256B coalesced
        int eidx = base + (l & 15);
        int jc   = start + min(eidx, dg - 1);
        int   sv  = csr_src[jc];
        float exS = (eidx < dg) ? csr_ex[(size_t)jc * 4 + (l >> 4)] : 0.f;
#pragma unroll
        for (int e = 0; e < 16; ++e) {
            int   s  = __shfl(sv, e);
            float ex = __shfl(exS, (h << 4) | e);
            ushort2 u = *(const ushort2*)&ft2[((size_t)s << 7) + (l << 1)];
            float f0, f1;
            {
                union { unsigned int i; float f; } c0, c1;
                c0.i = ((unsigned int)u.x) << 16;
                c1.i = ((unsigned int)u.y) << 16;
                f0 = c0.f; f1 = c1.f;
            }
            acc0 += ex * f0;
            acc1 += ex * f1;
            den  += ex;
        }
    }

    float a0 = (dg > 0) ? acc0 / den : 0.f;
    float a1 = (dg > 0) ? acc1 / den : 0.f;
    size_t o = (size_t)n * HD + (l << 1);
    *(float2*)&out_agg[o] = make_float2(a0, a1);
    float2 rr = *(const float2*)&out_rst[o];
    *(float2*)&out_rst[o] = make_float2(rr.x + a0, rr.y + a1);
}

// ---------------- launch
extern "C" void kernel_launch(void* const* d_in, const int* in_sizes, int n_in,
                              void* d_out, int out_size, void* d_ws, size_t ws_size,
                              hipStream_t stream) {
    const float* feat   = (const float*)d_in[0];
    const int*   src    = (const int*)d_in[1];
    const int*   dst    = (const int*)d_in[2];
    const float* fc_w   = (const float*)d_in[3];
    const float* attn_l = (const float*)d_in[4];
    const float* attn_r = (const float*)d_in[5];
    const float* res_w  = (const float*)d_in[6];

    float* out_rst = (float*)d_out;                       // [N][128]
    float* out_agg = out_rst + (size_t)NNODES * HD;       // [N][128]

    // workspace layout (256B aligned)
    char* p = (char*)d_ws;
    auto alloc = [&](size_t bytes) {
        char* r = p;
        p += (bytes + 255) & ~(size_t)255;
        return (void*)r;
    };
    __hip_bfloat16* ft = (__hip_bfloat16*)alloc((size_t)NNODES * HD * 2);  // 25.6 MB
    float* el        = (float*)alloc((size_t)NNODES * HH * 4);             // 1.6 MB
    float* er        = (float*)alloc((size_t)NNODES * HH * 4);             // 1.6 MB
    float* csr_ex    = (float*)alloc((size_t)NEDGES * HH * 4);             // 25.6 MB
    int*   deg       = (int*)alloc((size_t)NNODES * 4);
    int*   offsets   = (int*)alloc((size_t)NNODES * 4);
    int*   cursor    = (int*)alloc((size_t)NNODES * 4);
    int*   blockSums = (int*)alloc(1024);
    int*   csr_src   = (int*)alloc((size_t)NEDGES * 4);                    // 6.4 MB

    const int nb_scan = (NNODES + 1023) / 1024;                            // 98

    hipMemsetAsync(deg, 0, (size_t)NNODES * 4, stream);

    gemm_kernel<<<(NNODES + GBM - 1) / GBM, 256, 0, stream>>>(
        feat, fc_w, res_w, attn_l, attn_r, ft, out_rst, el, er);
    hist_kernel<<<(NEDGES + 255) / 256, 256, 0, stream>>>(dst, deg);
    scan1_kernel<<<nb_scan, 256, 0, stream>>>(deg, offsets, blockSums);
    scan2_kernel<<<1, 128, 0, stream>>>(blockSums, nb_scan);
    scan3_kernel<<<(NNODES + 255) / 256, 256, 0, stream>>>(offsets, cursor, blockSums);
    edge_kernel<<<(NEDGES + 255) / 256, 256, 0, stream>>>(src, dst, el, er, cursor, csr_src, csr_ex);
    agg_kernel<<<(NNODES + 3) / 4, 256, 0, stream>>>(offsets, deg, csr_src, csr_ex,
                                                     (const ushort*)ft, out_rst, out_agg);
}